// Round 13
// baseline (479.408 us; speedup 1.0000x reference)
//
#include <hip/hip_runtime.h>
#include <math.h>

// GIN: N=100000 nodes, E=1600000 edges, F=D=64, L=3 layers, C=10 classes.
// R26 = R25 (349.8us) + GEMM1 fused into the gather (k_aggemm):
//   gathers run at 27% HBM / 0% MFMA -- matrix pipe idle. Fused kernel:
//   block = 64 nodes, 4 waves; wave gathers its 16 nodes into a 64x72
//   bf16 LDS tile (was an HBM v16 write), then runs GEMM1 on its own
//   16-row tile (A via ds_read_b128, B = L1-hot precomputed Wh/Wl),
//   writes z1 + striped stats. Deletes 3 GEMM1 dispatches (~60us) and
//   the v16 round trip. Stats striping widened 8->32 slots (fused grid
//   is 1563 blocks; keeps <=49 serialized RMWs per address).

#define BN_EPS 1e-5f
#define NBKT 256     // dst buckets (dst>>9)
#define BCAP 12288   // per-bucket edge capacity (mean 8163, +45 sigma)
#define PCHUNK 4096  // edges per partition block
#define NSLOT 32     // stats striping slots

typedef __attribute__((ext_vector_type(8))) short bf16x8;
typedef __attribute__((ext_vector_type(4))) float f32x4;

__device__ __forceinline__ float bf2f(unsigned short u) {
  return __uint_as_float(((unsigned int)u) << 16);
}
__device__ __forceinline__ unsigned short f2bf(float x) {  // RNE
  unsigned int b = __float_as_uint(x);
  return (unsigned short)((b + 0x7FFFu + ((b >> 16) & 1u)) >> 16);
}

// sum the NSLOT contention slots of a striped stat row
__device__ __forceinline__ float stat32(const float* __restrict__ st, int i) {
  float s = 0.f;
#pragma unroll
  for (int k = 0; k < NSLOT; k++) s += st[k * 128 + i];
  return s;
}

// ---------- weight prep ----------

// once-per-launch: hi/lo bf16 split of all weights into swizzled [n][k].
// mats m=2l -> W1[l], m=2l+1 -> W2[l]; head: fcW[0..3] (cols n>=10 -> 0).
__global__ __launch_bounds__(256) void k_prep(
    const float* __restrict__ W1, const float* __restrict__ W2,
    const float* __restrict__ fcW, unsigned short* __restrict__ wh,
    unsigned short* __restrict__ wl, unsigned short* __restrict__ bh,
    unsigned short* __restrict__ bl) {
  int g = blockIdx.x * 256 + threadIdx.x;
  if (g < 6 * 4096) {
    int m = g >> 12, rem = g & 4095;
    int k = rem >> 6, n = rem & 63;
    const float* W = (m & 1) ? (W2 + (m >> 1) * 4096) : (W1 + (m >> 1) * 4096);
    float w = W[k * 64 + n];
    unsigned short hi = f2bf(w);
    float resid = w - bf2f(hi);
    int kx = (((k >> 3) ^ (n & 7)) << 3) + (k & 7);
    wh[m * 4096 + n * 64 + kx] = hi;
    wl[m * 4096 + n * 64 + kx] = f2bf(resid);
  } else {
    int g2 = g - 6 * 4096;  // [0, 4096)
    if (g2 < 4 * 1024) {
      int l = g2 >> 10, rem = g2 & 1023;
      int n = rem & 15, k = rem >> 4;
      float w = (n < 10) ? fcW[l * 640 + k * 10 + n] : 0.f;
      unsigned short hi = f2bf(w);
      float resid = w - bf2f(hi);
      int idx = l * 1024 + n * 64 + (((k >> 3) ^ (n & 7)) << 3) + (k & 7);
      bh[idx] = hi;
      bl[idx] = f2bf(resid);
    }
  }
}

// ---------- CSR build ----------

// blocks [0,nparts): partition edges into fixed-capacity dst-buckets
// (3KB LDS -> high occupancy); rest: x -> bf16 x16 convert (8 elems/thread).
__global__ __launch_bounds__(256) void k_part_conv(
    const int* __restrict__ src, const int* __restrict__ dst,
    int* __restrict__ bcur, int2* __restrict__ ep, int E, int nparts,
    const float* __restrict__ x, unsigned short* __restrict__ x16, int N) {
  __shared__ int lh[NBKT];
  __shared__ int lbase[NBKT];
  __shared__ int lcur[NBKT];
  int tid = threadIdx.x;
  if ((int)blockIdx.x < nparts) {
    int base = blockIdx.x * PCHUNK;
    int end = min(base + PCHUNK, E);
    lh[tid] = 0;
    lcur[tid] = 0;
    __syncthreads();
    for (int e = base + tid; e < end; e += 256) atomicAdd(&lh[dst[e] >> 9], 1);
    __syncthreads();
    int c = lh[tid];
    lbase[tid] = c ? (tid * BCAP + atomicAdd(&bcur[tid], c)) : 0;
    __syncthreads();
    for (int e = base + tid; e < end; e += 256) {
      int d = dst[e];
      int b = d >> 9;
      int r = atomicAdd(&lcur[b], 1);
      ep[lbase[b] + r] = make_int2(src[e], d);
    }
  } else {
    size_t g = ((size_t)blockIdx.x - nparts) * 256 + tid;
    size_t base = g * 8;
    if (base + 8 <= (size_t)N * 64) {
      float4 t0 = *(const float4*)(x + base);
      float4 t1 = *(const float4*)(x + base + 4);
      *(ushort4*)(x16 + base) =
          make_ushort4(f2bf(t0.x), f2bf(t0.y), f2bf(t0.z), f2bf(t0.w));
      *(ushort4*)(x16 + base + 4) =
          make_ushort4(f2bf(t1.x), f2bf(t1.y), f2bf(t1.z), f2bf(t1.w));
    }
  }
}

// per-bucket LDS counting sort. Emits offs, bend[b], csr. Blk 0 zeroes stats.
__global__ __launch_bounds__(256) void k_bucketsort(
    const int2* __restrict__ ep, const int* __restrict__ bcur,
    int* __restrict__ offs, int* __restrict__ bend, int* __restrict__ csr,
    float* __restrict__ stats) {
  __shared__ int cnt[512];
  __shared__ int ts[256];
  __shared__ int cur[512];
  int t = threadIdx.x;
  int b = blockIdx.x;
  if (b == 0) {
    for (int i = t; i < 6 * NSLOT * 128; i += 256) stats[i] = 0.f;
  }
  int lo = b * BCAP;
  int hi = lo + bcur[b];
  cnt[t] = 0;
  cnt[t + 256] = 0;
  __syncthreads();
  for (int e = lo + t; e < hi; e += 256) atomicAdd(&cnt[ep[e].y & 511], 1);
  __syncthreads();
  int c0 = cnt[2 * t], c1 = cnt[2 * t + 1];
  int s = c0 + c1;
  ts[t] = s;
  __syncthreads();
  for (int o = 1; o < 256; o <<= 1) {
    int add = (t >= o) ? ts[t - o] : 0;
    __syncthreads();
    ts[t] += add;
    __syncthreads();
  }
  int excl = ts[t] - s;
  cur[2 * t] = excl;
  cur[2 * t + 1] = excl + c0;
  int n0 = b << 9;
  offs[n0 + 2 * t] = lo + excl;
  offs[n0 + 2 * t + 1] = lo + excl + c0;
  if (t == 255) bend[b] = lo + ts[255];
  __syncthreads();
  for (int e = lo + t; e < hi; e += 256) {
    int2 p = ep[e];
    int pos = atomicAdd(&cur[p.y & 511], 1);
    csr[lo + pos] = p.x;
  }
}

// ---------- compute ----------

// 16-deep bf16 neighbor gather (no BN): sum of h16[src]
__device__ __forceinline__ float gather_plain(
    const unsigned short* __restrict__ h16, const int* __restrict__ csr,
    int e0, int e1, int lane) {
  float acc = 0.f;
  int e = e0;
  for (; e + 16 <= e1; e += 16) {
    int s0 = csr[e], s1 = csr[e + 1], s2 = csr[e + 2], s3 = csr[e + 3];
    int s4 = csr[e + 4], s5 = csr[e + 5], s6 = csr[e + 6], s7 = csr[e + 7];
    int s8 = csr[e + 8], s9 = csr[e + 9], sa = csr[e + 10], sb = csr[e + 11];
    int sc = csr[e + 12], sd = csr[e + 13], se = csr[e + 14], sf = csr[e + 15];
    float a0 = bf2f(h16[(size_t)s0 * 64 + lane]);
    float a1 = bf2f(h16[(size_t)s1 * 64 + lane]);
    float a2 = bf2f(h16[(size_t)s2 * 64 + lane]);
    float a3 = bf2f(h16[(size_t)s3 * 64 + lane]);
    float a4 = bf2f(h16[(size_t)s4 * 64 + lane]);
    float a5 = bf2f(h16[(size_t)s5 * 64 + lane]);
    float a6 = bf2f(h16[(size_t)s6 * 64 + lane]);
    float a7 = bf2f(h16[(size_t)s7 * 64 + lane]);
    float a8 = bf2f(h16[(size_t)s8 * 64 + lane]);
    float a9 = bf2f(h16[(size_t)s9 * 64 + lane]);
    float aa = bf2f(h16[(size_t)sa * 64 + lane]);
    float ab = bf2f(h16[(size_t)sb * 64 + lane]);
    float ac = bf2f(h16[(size_t)sc * 64 + lane]);
    float ad = bf2f(h16[(size_t)sd * 64 + lane]);
    float ae = bf2f(h16[(size_t)se * 64 + lane]);
    float af = bf2f(h16[(size_t)sf * 64 + lane]);
    acc += (((a0 + a1) + (a2 + a3)) + ((a4 + a5) + (a6 + a7))) +
           (((a8 + a9) + (aa + ab)) + ((ac + ad) + (ae + af)));
  }
  for (; e + 4 <= e1; e += 4) {
    int s0 = csr[e], s1 = csr[e + 1], s2 = csr[e + 2], s3 = csr[e + 3];
    float a0 = bf2f(h16[(size_t)s0 * 64 + lane]);
    float a1 = bf2f(h16[(size_t)s1 * 64 + lane]);
    float a2 = bf2f(h16[(size_t)s2 * 64 + lane]);
    float a3 = bf2f(h16[(size_t)s3 * 64 + lane]);
    acc += (a0 + a1) + (a2 + a3);
  }
  for (; e < e1; e++) acc += bf2f(h16[(size_t)csr[e] * 64 + lane]);
  return acc;
}

// 16-deep bf16 neighbor gather with BN+ReLU: sum of relu(h16[src]*A+B)
__device__ __forceinline__ float gather_bn(
    const unsigned short* __restrict__ h16, const int* __restrict__ csr,
    int e0, int e1, int lane, float A, float B) {
  float acc = 0.f;
  int e = e0;
  for (; e + 16 <= e1; e += 16) {
    int s0 = csr[e], s1 = csr[e + 1], s2 = csr[e + 2], s3 = csr[e + 3];
    int s4 = csr[e + 4], s5 = csr[e + 5], s6 = csr[e + 6], s7 = csr[e + 7];
    int s8 = csr[e + 8], s9 = csr[e + 9], sa = csr[e + 10], sb = csr[e + 11];
    int sc = csr[e + 12], sd = csr[e + 13], se = csr[e + 14], sf = csr[e + 15];
    float a0 = bf2f(h16[(size_t)s0 * 64 + lane]);
    float a1 = bf2f(h16[(size_t)s1 * 64 + lane]);
    float a2 = bf2f(h16[(size_t)s2 * 64 + lane]);
    float a3 = bf2f(h16[(size_t)s3 * 64 + lane]);
    float a4 = bf2f(h16[(size_t)s4 * 64 + lane]);
    float a5 = bf2f(h16[(size_t)s5 * 64 + lane]);
    float a6 = bf2f(h16[(size_t)s6 * 64 + lane]);
    float a7 = bf2f(h16[(size_t)s7 * 64 + lane]);
    float a8 = bf2f(h16[(size_t)s8 * 64 + lane]);
    float a9 = bf2f(h16[(size_t)s9 * 64 + lane]);
    float aa = bf2f(h16[(size_t)sa * 64 + lane]);
    float ab = bf2f(h16[(size_t)sb * 64 + lane]);
    float ac = bf2f(h16[(size_t)sc * 64 + lane]);
    float ad = bf2f(h16[(size_t)sd * 64 + lane]);
    float ae = bf2f(h16[(size_t)se * 64 + lane]);
    float af = bf2f(h16[(size_t)sf * 64 + lane]);
    a0 = fmaxf(a0 * A + B, 0.f); a1 = fmaxf(a1 * A + B, 0.f);
    a2 = fmaxf(a2 * A + B, 0.f); a3 = fmaxf(a3 * A + B, 0.f);
    a4 = fmaxf(a4 * A + B, 0.f); a5 = fmaxf(a5 * A + B, 0.f);
    a6 = fmaxf(a6 * A + B, 0.f); a7 = fmaxf(a7 * A + B, 0.f);
    a8 = fmaxf(a8 * A + B, 0.f); a9 = fmaxf(a9 * A + B, 0.f);
    aa = fmaxf(aa * A + B, 0.f); ab = fmaxf(ab * A + B, 0.f);
    ac = fmaxf(ac * A + B, 0.f); ad = fmaxf(ad * A + B, 0.f);
    ae = fmaxf(ae * A + B, 0.f); af = fmaxf(af * A + B, 0.f);
    acc += (((a0 + a1) + (a2 + a3)) + ((a4 + a5) + (a6 + a7))) +
           (((a8 + a9) + (aa + ab)) + ((ac + ad) + (ae + af)));
  }
  for (; e + 4 <= e1; e += 4) {
    int s0 = csr[e], s1 = csr[e + 1], s2 = csr[e + 2], s3 = csr[e + 3];
    float a0 = bf2f(h16[(size_t)s0 * 64 + lane]);
    float a1 = bf2f(h16[(size_t)s1 * 64 + lane]);
    float a2 = bf2f(h16[(size_t)s2 * 64 + lane]);
    float a3 = bf2f(h16[(size_t)s3 * 64 + lane]);
    a0 = fmaxf(a0 * A + B, 0.f); a1 = fmaxf(a1 * A + B, 0.f);
    a2 = fmaxf(a2 * A + B, 0.f); a3 = fmaxf(a3 * A + B, 0.f);
    acc += (a0 + a1) + (a2 + a3);
  }
  for (; e < e1; e++) {
    float a = bf2f(h16[(size_t)csr[e] * 64 + lane]);
    acc += fmaxf(a * A + B, 0.f);
  }
  return acc;
}

// fused aggregation + GEMM1. Block = 64 nodes, 4 waves; wave w gathers its
// 16 nodes (lane = feature) into LDS rows [w*16 .. w*16+15], then runs the
// 16x64x64 GEMM1 tile on them (A from LDS, B = L1-hot Wh/Wl), writes z1
// bf16 + striped column stats. DOBN: apply BN+ReLU of the input (layers>0).
template <bool DOBN>
__global__ __launch_bounds__(256) void k_aggemm(
    const unsigned short* __restrict__ h16, const float* __restrict__ stats_in,
    const float* __restrict__ gv, const float* __restrict__ bev,
    const int* __restrict__ offs, const int* __restrict__ bend,
    const int* __restrict__ csr, const unsigned short* __restrict__ Wh,
    const unsigned short* __restrict__ Wl, unsigned short* __restrict__ zout,
    float* __restrict__ stats_out, int N) {
  __shared__ float ABs[128];
  __shared__ float red[512];
  __shared__ __align__(16) unsigned short vlds[64 * 72];
  int tid = threadIdx.x;
  if (DOBN) {
    if (tid < 64) {
      float inv_n = 1.f / (float)N;
      float mu = stat32(stats_in, tid) * inv_n;
      float var = stat32(stats_in, 64 + tid) * inv_n - mu * mu;
      float A = rsqrtf(var + BN_EPS) * gv[tid];
      ABs[tid] = A;
      ABs[64 + tid] = bev[tid] - mu * A;
    }
    __syncthreads();
  }
  int wv = tid >> 6, lane = tid & 63;
  int nbase = blockIdx.x * 64 + wv * 16;
  float A = DOBN ? ABs[lane] : 1.f;
  float B = DOBN ? ABs[64 + lane] : 0.f;
  unsigned short* vw = vlds + (size_t)wv * 16 * 72;

  // gather phase: 16 nodes per wave, lane = feature
#pragma unroll 1
  for (int i = 0; i < 16; i++) {
    int node = nbase + i;
    float val = 0.f;
    if (node < N) {
      int e0 = offs[node];
      int e1 = ((node & 511) == 511) ? bend[node >> 9] : offs[node + 1];
      float sv = bf2f(h16[(size_t)node * 64 + lane]);
      if (DOBN) {
        val = fmaxf(sv * A + B, 0.f) + gather_bn(h16, csr, e0, e1, lane, A, B);
      } else {
        val = sv + gather_plain(h16, csr, e0, e1, lane);
      }
    }
    vw[i * 72 + lane] = f2bf(val);
  }

  // GEMM1 phase: wave's own 16-row tile (no barrier needed; wave-local LDS)
  int c = lane & 15, q = lane >> 4;
  bf16x8 af[2];
#pragma unroll
  for (int kb = 0; kb < 2; kb++)
    af[kb] = *(const bf16x8*)(vlds + ((size_t)wv * 16 + c) * 72 + kb * 32 +
                              q * 8);
  f32x4 acc[4];
#pragma unroll
  for (int nt = 0; nt < 4; nt++) acc[nt] = (f32x4){0.f, 0.f, 0.f, 0.f};
#pragma unroll
  for (int nt = 0; nt < 4; nt++) {
    int cn = nt * 16 + c;
#pragma unroll
    for (int kb = 0; kb < 2; kb++) {
      int kx = (((kb * 4 + q) ^ (cn & 7)) << 3);
      bf16x8 bhi = *(const bf16x8*)(Wh + cn * 64 + kx);
      bf16x8 blo = *(const bf16x8*)(Wl + cn * 64 + kx);
      acc[nt] = __builtin_amdgcn_mfma_f32_16x16x32_bf16(af[kb], bhi, acc[nt],
                                                        0, 0, 0);
      acc[nt] = __builtin_amdgcn_mfma_f32_16x16x32_bf16(af[kb], blo, acc[nt],
                                                        0, 0, 0);
    }
  }
  // store z1 (bf16): lane holds rows 4q+r, col nt*16+c
#pragma unroll
  for (int r = 0; r < 4; r++) {
    int row = nbase + q * 4 + r;
    if (row < N) {
      unsigned short* zr = zout + (size_t)row * 64 + c;
      zr[0] = f2bf(acc[0][r]);
      zr[16] = f2bf(acc[1][r]);
      zr[32] = f2bf(acc[2][r]);
      zr[48] = f2bf(acc[3][r]);
    }
  }
  // column sum / sumsq (phantom rows exact 0)
  float cs[4], cq[4];
#pragma unroll
  for (int nt = 0; nt < 4; nt++) {
    float s = 0.f, s2 = 0.f;
#pragma unroll
    for (int r = 0; r < 4; r++) {
      float v = acc[nt][r];
      s += v;
      s2 += v * v;
    }
    s += __shfl_xor(s, 16);
    s += __shfl_xor(s, 32);
    s2 += __shfl_xor(s2, 16);
    s2 += __shfl_xor(s2, 32);
    cs[nt] = s;
    cq[nt] = s2;
  }
  if (lane < 16) {
#pragma unroll
    for (int nt = 0; nt < 4; nt++) {
      red[wv * 128 + nt * 16 + lane] = cs[nt];
      red[wv * 128 + 64 + nt * 16 + lane] = cq[nt];
    }
  }
  __syncthreads();
  if (tid < 64) {
    float a = red[tid] + red[128 + tid] + red[256 + tid] + red[384 + tid];
    float b = red[64 + tid] + red[192 + tid] + red[320 + tid] + red[448 + tid];
    float* so = stats_out + (blockIdx.x & (NSLOT - 1)) * 128;
    atomicAdd(&so[tid], a);
    atomicAdd(&so[64 + tid], b);
  }
}

// MFMA GEMM: 256 rows/block, 4 waves, wave = 64 rows x 64 cols.
// A: bf16 fragments straight from global (BN+ReLU in-register if dobn).
// B: hi/lo bf16 fragments from precomputed global W16 (L1-hot).
// Epilogue: bf16 z store + fp32 column sum/sumsq -> striped stats_out.
__global__ __launch_bounds__(256) void k_gemm2(
    const unsigned short* __restrict__ vin, unsigned short* __restrict__ zout,
    const unsigned short* __restrict__ Wh, const unsigned short* __restrict__ Wl,
    const float* __restrict__ stats_in, const float* __restrict__ gv,
    const float* __restrict__ bev, int dobn,
    float* __restrict__ stats_out, int N) {
  __shared__ float ABs[128];
  __shared__ float red[512];
  int tid = threadIdx.x;
  int n0 = blockIdx.x * 256;
  if (dobn) {
    if (tid < 64) {
      float inv_n = 1.f / (float)N;
      float mu = stat32(stats_in, tid) * inv_n;
      float var = stat32(stats_in, 64 + tid) * inv_n - mu * mu;
      float A = rsqrtf(var + BN_EPS) * gv[tid];
      ABs[tid] = A;
      ABs[64 + tid] = bev[tid] - mu * A;
    }
    __syncthreads();
  }

  int wv = tid >> 6;
  int lane = tid & 63;
  int c = lane & 15;  // col in 16-tile / row in A m-tile
  int q = lane >> 4;  // k-group
  int wrow = n0 + wv * 64;

  // A fragments: a[mt][kb], row = wrow + mt*16 + c, k = kb*32 + 8q + j
  bf16x8 afrag[4][2];
#pragma unroll
  for (int mt = 0; mt < 4; mt++) {
    int row = wrow + mt * 16 + c;
#pragma unroll
    for (int kb = 0; kb < 2; kb++) {
      int col0 = kb * 32 + q * 8;
      bf16x8 a = {0, 0, 0, 0, 0, 0, 0, 0};
      if (row < N) {
        a = *(const bf16x8*)(vin + (size_t)row * 64 + col0);
        if (dobn) {
#pragma unroll
          for (int j = 0; j < 8; j++) {
            float f = bf2f((unsigned short)a[j]) * ABs[col0 + j] +
                      ABs[64 + col0 + j];
            a[j] = (short)f2bf(fmaxf(f, 0.f));
          }
        }
      }
      afrag[mt][kb] = a;
    }
  }

  f32x4 acc[4][4];
#pragma unroll
  for (int mt = 0; mt < 4; mt++)
#pragma unroll
    for (int nt = 0; nt < 4; nt++)
      acc[mt][nt] = (f32x4){0.f, 0.f, 0.f, 0.f};

#pragma unroll
  for (int nt = 0; nt < 4; nt++) {
    int cn = nt * 16 + c;
#pragma unroll
    for (int kb = 0; kb < 2; kb++) {
      int kchunk = kb * 4 + q;
      int kx = ((kchunk ^ (cn & 7)) << 3);
      bf16x8 bhi = *(const bf16x8*)(Wh + cn * 64 + kx);
      bf16x8 blo = *(const bf16x8*)(Wl + cn * 64 + kx);
#pragma unroll
      for (int mt = 0; mt < 4; mt++) {
        acc[mt][nt] = __builtin_amdgcn_mfma_f32_16x16x32_bf16(
            afrag[mt][kb], bhi, acc[mt][nt], 0, 0, 0);
        acc[mt][nt] = __builtin_amdgcn_mfma_f32_16x16x32_bf16(
            afrag[mt][kb], blo, acc[mt][nt], 0, 0, 0);
      }
    }
  }

  // store z (bf16): lane holds rows 4q+r, col nt*16+c
#pragma unroll
  for (int mt = 0; mt < 4; mt++) {
#pragma unroll
    for (int r = 0; r < 4; r++) {
      int row = wrow + mt * 16 + q * 4 + r;
      if (row < N) {
        unsigned short* zr = zout + (size_t)row * 64 + c;
        zr[0] = f2bf(acc[mt][0][r]);
        zr[16] = f2bf(acc[mt][1][r]);
        zr[32] = f2bf(acc[mt][2][r]);
        zr[48] = f2bf(acc[mt][3][r]);
      }
    }
  }

  // column sum / sumsq over this block's rows (phantom rows are exact 0)
  float cs[4], cq[4];
#pragma unroll
  for (int nt = 0; nt < 4; nt++) {
    float s = 0.f, s2 = 0.f;
#pragma unroll
    for (int mt = 0; mt < 4; mt++)
#pragma unroll
      for (int r = 0; r < 4; r++) {
        float v = acc[mt][nt][r];
        s += v;
        s2 += v * v;
      }
    s += __shfl_xor(s, 16);
    s += __shfl_xor(s, 32);
    s2 += __shfl_xor(s2, 16);
    s2 += __shfl_xor(s2, 32);
    cs[nt] = s;
    cq[nt] = s2;
  }
  if (lane < 16) {
#pragma unroll
    for (int nt = 0; nt < 4; nt++) {
      red[wv * 128 + nt * 16 + lane] = cs[nt];
      red[wv * 128 + 64 + nt * 16 + lane] = cq[nt];
    }
  }
  __syncthreads();
  if (tid < 64) {
    float a = red[tid] + red[128 + tid] + red[256 + tid] + red[384 + tid];
    float b = red[64 + tid] + red[192 + tid] + red[320 + tid] + red[448 + tid];
    float* so = stats_out + (blockIdx.x & (NSLOT - 1)) * 128;
    atomicAdd(&so[tid], a);
    atomicAdd(&so[64 + tid], b);
  }
}

// JK heads on MFMA, 4 terms: out[n] = lsm(x@fcW0 + sum_l relu(bn(z_l))@fcW_{l+1}
//                                        + sum_l fcb_l)
// 128 rows/block, 4 waves; B-fragments from precomputed global bh/bl.
__global__ __launch_bounds__(256) void k_head_mfma(
    const unsigned short* __restrict__ x16,
    const unsigned short* __restrict__ z0, const unsigned short* __restrict__ z1,
    const unsigned short* __restrict__ z2, const float* __restrict__ stats,
    const float* __restrict__ gbn, const float* __restrict__ bbn,
    const unsigned short* __restrict__ bh, const unsigned short* __restrict__ bl,
    const float* __restrict__ fcb, float* __restrict__ out, int N) {
  __shared__ float ABs[3 * 128];
  int tid = threadIdx.x;
  if (tid < 64) {
    float inv_n = 1.f / (float)N;
#pragma unroll
    for (int l = 0; l < 3; l++) {
      const float* st = stats + (2 * l + 1) * (NSLOT * 128);
      float mu = stat32(st, tid) * inv_n;
      float var = stat32(st, 64 + tid) * inv_n - mu * mu;
      float A = rsqrtf(var + BN_EPS) * gbn[l * 64 + tid];
      ABs[l * 128 + tid] = A;
      ABs[l * 128 + 64 + tid] = bbn[l * 64 + tid] - mu * A;
    }
  }
  __syncthreads();

  int wv = tid >> 6, lane = tid & 63;
  int c = lane & 15, q = lane >> 4;
  int wrow = blockIdx.x * 128 + wv * 32;

  f32x4 acc[2];
  acc[0] = (f32x4){0.f, 0.f, 0.f, 0.f};
  acc[1] = (f32x4){0.f, 0.f, 0.f, 0.f};
#pragma unroll
  for (int l = 0; l < 4; l++) {
    const unsigned short* z = (l == 0) ? x16 : (l == 1) ? z0 : (l == 2) ? z1
                                                                       : z2;
#pragma unroll
    for (int kb = 0; kb < 2; kb++) {
      int kchunk = kb * 4 + q;
      int kx = ((kchunk ^ (c & 7)) << 3);
      bf16x8 bh_ = *(const bf16x8*)(bh + l * 1024 + c * 64 + kx);
      bf16x8 bl_ = *(const bf16x8*)(bl + l * 1024 + c * 64 + kx);
      int col0 = kb * 32 + q * 8;
#pragma unroll
      for (int mt = 0; mt < 2; mt++) {
        int row = wrow + mt * 16 + c;
        bf16x8 a = {0, 0, 0, 0, 0, 0, 0, 0};
        if (row < N) {
          a = *(const bf16x8*)(z + (size_t)row * 64 + col0);
          if (l > 0) {
            const float* AB = ABs + (l - 1) * 128;
#pragma unroll
            for (int j = 0; j < 8; j++) {
              float f = bf2f((unsigned short)a[j]) * AB[col0 + j] +
                        AB[64 + col0 + j];
              a[j] = (short)f2bf(fmaxf(f, 0.f));
            }
          }
        }
        acc[mt] = __builtin_amdgcn_mfma_f32_16x16x32_bf16(a, bh_, acc[mt],
                                                          0, 0, 0);
        acc[mt] = __builtin_amdgcn_mfma_f32_16x16x32_bf16(a, bl_, acc[mt],
                                                          0, 0, 0);
      }
    }
  }
  // epilogue: + sum_l fcb, log_softmax over cols (c<10), write out
  float cb = 0.f;
  if (c < 10) cb = fcb[c] + fcb[10 + c] + fcb[20 + c] + fcb[30 + c];
#pragma unroll
  for (int mt = 0; mt < 2; mt++) {
    float v[4], vm[4];
#pragma unroll
    for (int r = 0; r < 4; r++) {
      v[r] = acc[mt][r] + cb;
      vm[r] = (c < 10) ? v[r] : -INFINITY;
    }
#pragma unroll
    for (int off = 1; off < 16; off <<= 1) {
#pragma unroll
      for (int r = 0; r < 4; r++) vm[r] = fmaxf(vm[r], __shfl_xor(vm[r], off));
    }
    float sm[4];
#pragma unroll
    for (int r = 0; r < 4; r++) sm[r] = (c < 10) ? expf(v[r] - vm[r]) : 0.f;
#pragma unroll
    for (int off = 1; off < 16; off <<= 1) {
#pragma unroll
      for (int r = 0; r < 4; r++) sm[r] += __shfl_xor(sm[r], off);
    }
#pragma unroll
    for (int r = 0; r < 4; r++) {
      int row = wrow + mt * 16 + q * 4 + r;
      if (row < N && c < 10)
        out[(size_t)row * 10 + c] = v[r] - (logf(sm[r]) + vm[r]);
    }
  }
}

extern "C" void kernel_launch(void* const* d_in, const int* in_sizes, int n_in,
                              void* d_out, int out_size, void* d_ws, size_t ws_size,
                              hipStream_t stream) {
  const float* x = (const float*)d_in[0];
  const int* ei = (const int*)d_in[1];
  const float* W1 = (const float*)d_in[2];
  const float* g1 = (const float*)d_in[4];
  const float* be1 = (const float*)d_in[5];
  const float* W2 = (const float*)d_in[6];
  const float* gbn = (const float*)d_in[8];
  const float* bbn = (const float*)d_in[9];
  const float* fcW = (const float*)d_in[10];
  const float* fcb = (const float*)d_in[11];
  float* out = (float*)d_out;

  const int N = in_sizes[0] / 64;
  const int E = in_sizes[1] / 2;
  const int* src = ei;
  const int* dst = ei + E;

  char* ws = (char*)d_ws;
  size_t off = 0;
  auto alloc = [&](size_t bytes) -> void* {
    void* p = ws + off;
    off = (off + bytes + 255) & ~(size_t)255;
    return p;
  };
  int* bcur = (int*)alloc(NBKT * 4);  // zeroed by memset node
  float* stats = (float*)alloc(6 * NSLOT * 128 * 4);  // zeroed by bucketsort
  int* offs = (int*)alloc((size_t)NBKT * 512 * 4);
  int* bend = (int*)alloc(NBKT * 4);
  int* csr = (int*)alloc((size_t)NBKT * BCAP * 4);
  unsigned short* w16h = (unsigned short*)alloc(6 * 4096 * 2);
  unsigned short* w16l = (unsigned short*)alloc(6 * 4096 * 2);
  unsigned short* bh16 = (unsigned short*)alloc(4 * 1024 * 2);
  unsigned short* bl16 = (unsigned short*)alloc(4 * 1024 * 2);
  unsigned short* x16 = (unsigned short*)alloc((size_t)N * 64 * 2);
  unsigned short* z1_16 = (unsigned short*)alloc((size_t)N * 64 * 2);
  unsigned short* z16a = (unsigned short*)alloc((size_t)N * 64 * 2);
  unsigned short* z16b = (unsigned short*)alloc((size_t)N * 64 * 2);
  unsigned short* z16c = (unsigned short*)alloc((size_t)N * 64 * 2);
  int2* ep = (int2*)alloc((size_t)NBKT * BCAP * 8);
  (void)ws_size;
  (void)n_in;
  (void)out_size;

  unsigned short* z16l_[3] = {z16a, z16b, z16c};
  int gb = (N + 127) / 128;
  int gb2 = (N + 255) / 256;
  int fb = (N + 63) / 64;
  int nparts = (E + PCHUNK - 1) / PCHUNK;
  int nconv = (N * 64 / 8 + 255) / 256;
  hipMemsetAsync(bcur, 0, NBKT * 4, stream);
  k_prep<<<112, 256, 0, stream>>>(W1, W2, fcW, w16h, w16l, bh16, bl16);
  k_part_conv<<<nparts + nconv, 256, 0, stream>>>(src, dst, bcur, ep, E,
                                                  nparts, x, x16, N);
  k_bucketsort<<<NBKT, 256, 0, stream>>>(ep, bcur, offs, bend, csr, stats);

  for (int l = 0; l < 3; l++) {
    float* st1 = stats + (2 * l) * (NSLOT * 128);
    float* st2 = stats + (2 * l + 1) * (NSLOT * 128);
    if (l == 0) {
      k_aggemm<false><<<fb, 256, 0, stream>>>(
          x16, nullptr, nullptr, nullptr, offs, bend, csr,
          w16h + (2 * l) * 4096, w16l + (2 * l) * 4096, z1_16, st1, N);
    } else {
      float* st2p = stats + (2 * (l - 1) + 1) * (NSLOT * 128);
      k_aggemm<true><<<fb, 256, 0, stream>>>(
          z16l_[l - 1], st2p, gbn + (l - 1) * 64, bbn + (l - 1) * 64, offs,
          bend, csr, w16h + (2 * l) * 4096, w16l + (2 * l) * 4096, z1_16, st1,
          N);
    }
    k_gemm2<<<gb2, 256, 0, stream>>>(z1_16, z16l_[l], w16h + (2 * l + 1) * 4096,
                                     w16l + (2 * l + 1) * 4096, st1,
                                     g1 + l * 64, be1 + l * 64, 1, st2, N);
  }
  k_head_mfma<<<gb, 256, 0, stream>>>(x16, z16a, z16b, z16c, stats, gbn, bbn,
                                      bh16, bl16, fcb, out, N);
}

// Round 14
// 372.590 us; speedup vs baseline: 1.2867x; 1.2867x over previous
//
#include <hip/hip_runtime.h>
#include <math.h>

// GIN: N=100000 nodes, E=1600000 edges, F=D=64, L=3 layers, C=10 classes.
// R27 = R25 restore (best measured 349.8us) + 32-slot stats striping.
//   R26's gather+GEMM1 fusion regressed 350->479: 16-nodes-serial-per-wave
//   destroyed the gather's memory-level parallelism (0.95 vs 2.2 TB/s,
//   occ 33% vs 65%). Gather needs one-node-per-wave granularity.
//   Components (each the winner of its A/B history):
//   - partition+bucketsort CSR build, one-node-per-wave gather_plain aggs,
//   - 256-row MFMA gemm2 w/ precomputed hi/lo bf16 weights,
//   - 4-term MFMA head, striped BN-stats atomics (now 32 slots).

#define BN_EPS 1e-5f
#define NBKT 256     // dst buckets (dst>>9)
#define BCAP 12288   // per-bucket edge capacity (mean 8163, +45 sigma)
#define PCHUNK 4096  // edges per partition block
#define NSLOT 32     // stats striping slots

typedef __attribute__((ext_vector_type(8))) short bf16x8;
typedef __attribute__((ext_vector_type(4))) float f32x4;

__device__ __forceinline__ float bf2f(unsigned short u) {
  return __uint_as_float(((unsigned int)u) << 16);
}
__device__ __forceinline__ unsigned short f2bf(float x) {  // RNE
  unsigned int b = __float_as_uint(x);
  return (unsigned short)((b + 0x7FFFu + ((b >> 16) & 1u)) >> 16);
}

// sum the NSLOT contention slots of a striped stat row
__device__ __forceinline__ float stat32(const float* __restrict__ st, int i) {
  float s = 0.f;
#pragma unroll
  for (int k = 0; k < NSLOT; k++) s += st[k * 128 + i];
  return s;
}

// ---------- weight prep ----------

// once-per-launch: hi/lo bf16 split of all weights into swizzled [n][k].
// mats m=2l -> W1[l], m=2l+1 -> W2[l]; head: fcW[0..3] (cols n>=10 -> 0).
__global__ __launch_bounds__(256) void k_prep(
    const float* __restrict__ W1, const float* __restrict__ W2,
    const float* __restrict__ fcW, unsigned short* __restrict__ wh,
    unsigned short* __restrict__ wl, unsigned short* __restrict__ bh,
    unsigned short* __restrict__ bl) {
  int g = blockIdx.x * 256 + threadIdx.x;
  if (g < 6 * 4096) {
    int m = g >> 12, rem = g & 4095;
    int k = rem >> 6, n = rem & 63;
    const float* W = (m & 1) ? (W2 + (m >> 1) * 4096) : (W1 + (m >> 1) * 4096);
    float w = W[k * 64 + n];
    unsigned short hi = f2bf(w);
    float resid = w - bf2f(hi);
    int kx = (((k >> 3) ^ (n & 7)) << 3) + (k & 7);
    wh[m * 4096 + n * 64 + kx] = hi;
    wl[m * 4096 + n * 64 + kx] = f2bf(resid);
  } else {
    int g2 = g - 6 * 4096;  // [0, 4096)
    if (g2 < 4 * 1024) {
      int l = g2 >> 10, rem = g2 & 1023;
      int n = rem & 15, k = rem >> 4;
      float w = (n < 10) ? fcW[l * 640 + k * 10 + n] : 0.f;
      unsigned short hi = f2bf(w);
      float resid = w - bf2f(hi);
      int idx = l * 1024 + n * 64 + (((k >> 3) ^ (n & 7)) << 3) + (k & 7);
      bh[idx] = hi;
      bl[idx] = f2bf(resid);
    }
  }
}

// ---------- CSR build ----------

// blocks [0,nparts): partition edges into fixed-capacity dst-buckets
// (3KB LDS -> high occupancy); rest: x -> bf16 x16 convert (8 elems/thread).
__global__ __launch_bounds__(256) void k_part_conv(
    const int* __restrict__ src, const int* __restrict__ dst,
    int* __restrict__ bcur, int2* __restrict__ ep, int E, int nparts,
    const float* __restrict__ x, unsigned short* __restrict__ x16, int N) {
  __shared__ int lh[NBKT];
  __shared__ int lbase[NBKT];
  __shared__ int lcur[NBKT];
  int tid = threadIdx.x;
  if ((int)blockIdx.x < nparts) {
    int base = blockIdx.x * PCHUNK;
    int end = min(base + PCHUNK, E);
    lh[tid] = 0;
    lcur[tid] = 0;
    __syncthreads();
    for (int e = base + tid; e < end; e += 256) atomicAdd(&lh[dst[e] >> 9], 1);
    __syncthreads();
    int c = lh[tid];
    lbase[tid] = c ? (tid * BCAP + atomicAdd(&bcur[tid], c)) : 0;
    __syncthreads();
    for (int e = base + tid; e < end; e += 256) {
      int d = dst[e];
      int b = d >> 9;
      int r = atomicAdd(&lcur[b], 1);
      ep[lbase[b] + r] = make_int2(src[e], d);
    }
  } else {
    size_t g = ((size_t)blockIdx.x - nparts) * 256 + tid;
    size_t base = g * 8;
    if (base + 8 <= (size_t)N * 64) {
      float4 t0 = *(const float4*)(x + base);
      float4 t1 = *(const float4*)(x + base + 4);
      *(ushort4*)(x16 + base) =
          make_ushort4(f2bf(t0.x), f2bf(t0.y), f2bf(t0.z), f2bf(t0.w));
      *(ushort4*)(x16 + base + 4) =
          make_ushort4(f2bf(t1.x), f2bf(t1.y), f2bf(t1.z), f2bf(t1.w));
    }
  }
}

// per-bucket LDS counting sort. Emits offs, bend[b], csr. Blk 0 zeroes stats.
__global__ __launch_bounds__(256) void k_bucketsort(
    const int2* __restrict__ ep, const int* __restrict__ bcur,
    int* __restrict__ offs, int* __restrict__ bend, int* __restrict__ csr,
    float* __restrict__ stats) {
  __shared__ int cnt[512];
  __shared__ int ts[256];
  __shared__ int cur[512];
  int t = threadIdx.x;
  int b = blockIdx.x;
  if (b == 0) {
    for (int i = t; i < 6 * NSLOT * 128; i += 256) stats[i] = 0.f;
  }
  int lo = b * BCAP;
  int hi = lo + bcur[b];
  cnt[t] = 0;
  cnt[t + 256] = 0;
  __syncthreads();
  for (int e = lo + t; e < hi; e += 256) atomicAdd(&cnt[ep[e].y & 511], 1);
  __syncthreads();
  int c0 = cnt[2 * t], c1 = cnt[2 * t + 1];
  int s = c0 + c1;
  ts[t] = s;
  __syncthreads();
  for (int o = 1; o < 256; o <<= 1) {
    int add = (t >= o) ? ts[t - o] : 0;
    __syncthreads();
    ts[t] += add;
    __syncthreads();
  }
  int excl = ts[t] - s;
  cur[2 * t] = excl;
  cur[2 * t + 1] = excl + c0;
  int n0 = b << 9;
  offs[n0 + 2 * t] = lo + excl;
  offs[n0 + 2 * t + 1] = lo + excl + c0;
  if (t == 255) bend[b] = lo + ts[255];
  __syncthreads();
  for (int e = lo + t; e < hi; e += 256) {
    int2 p = ep[e];
    int pos = atomicAdd(&cur[p.y & 511], 1);
    csr[lo + pos] = p.x;
  }
}

// ---------- compute ----------

// 16-deep bf16 neighbor gather (no BN): sum of h16[src]
__device__ __forceinline__ float gather_plain(
    const unsigned short* __restrict__ h16, const int* __restrict__ csr,
    int e0, int e1, int lane) {
  float acc = 0.f;
  int e = e0;
  for (; e + 16 <= e1; e += 16) {
    int s0 = csr[e], s1 = csr[e + 1], s2 = csr[e + 2], s3 = csr[e + 3];
    int s4 = csr[e + 4], s5 = csr[e + 5], s6 = csr[e + 6], s7 = csr[e + 7];
    int s8 = csr[e + 8], s9 = csr[e + 9], sa = csr[e + 10], sb = csr[e + 11];
    int sc = csr[e + 12], sd = csr[e + 13], se = csr[e + 14], sf = csr[e + 15];
    float a0 = bf2f(h16[(size_t)s0 * 64 + lane]);
    float a1 = bf2f(h16[(size_t)s1 * 64 + lane]);
    float a2 = bf2f(h16[(size_t)s2 * 64 + lane]);
    float a3 = bf2f(h16[(size_t)s3 * 64 + lane]);
    float a4 = bf2f(h16[(size_t)s4 * 64 + lane]);
    float a5 = bf2f(h16[(size_t)s5 * 64 + lane]);
    float a6 = bf2f(h16[(size_t)s6 * 64 + lane]);
    float a7 = bf2f(h16[(size_t)s7 * 64 + lane]);
    float a8 = bf2f(h16[(size_t)s8 * 64 + lane]);
    float a9 = bf2f(h16[(size_t)s9 * 64 + lane]);
    float aa = bf2f(h16[(size_t)sa * 64 + lane]);
    float ab = bf2f(h16[(size_t)sb * 64 + lane]);
    float ac = bf2f(h16[(size_t)sc * 64 + lane]);
    float ad = bf2f(h16[(size_t)sd * 64 + lane]);
    float ae = bf2f(h16[(size_t)se * 64 + lane]);
    float af = bf2f(h16[(size_t)sf * 64 + lane]);
    acc += (((a0 + a1) + (a2 + a3)) + ((a4 + a5) + (a6 + a7))) +
           (((a8 + a9) + (aa + ab)) + ((ac + ad) + (ae + af)));
  }
  for (; e + 4 <= e1; e += 4) {
    int s0 = csr[e], s1 = csr[e + 1], s2 = csr[e + 2], s3 = csr[e + 3];
    float a0 = bf2f(h16[(size_t)s0 * 64 + lane]);
    float a1 = bf2f(h16[(size_t)s1 * 64 + lane]);
    float a2 = bf2f(h16[(size_t)s2 * 64 + lane]);
    float a3 = bf2f(h16[(size_t)s3 * 64 + lane]);
    acc += (a0 + a1) + (a2 + a3);
  }
  for (; e < e1; e++) acc += bf2f(h16[(size_t)csr[e] * 64 + lane]);
  return acc;
}

// layer-0 aggregation: v16[n] = bf16(x16[n] + sum x16[src])
__global__ __launch_bounds__(256) void k_agg(
    const unsigned short* __restrict__ h16, const int* __restrict__ offs,
    const int* __restrict__ bend, const int* __restrict__ csr,
    unsigned short* __restrict__ vout, int N) {
  int gid = blockIdx.x * blockDim.x + threadIdx.x;
  int wid = __builtin_amdgcn_readfirstlane(gid >> 6);
  int lane = threadIdx.x & 63;
  if (wid >= N) return;
  int e0 = offs[wid];
  int e1 = ((wid & 511) == 511) ? bend[wid >> 9] : offs[wid + 1];
  float acc = bf2f(h16[(size_t)wid * 64 + lane]) +
              gather_plain(h16, csr, e0, e1, lane);
  vout[(size_t)wid * 64 + lane] = f2bf(acc);
}

// BN+ReLU aggregation: v16[n] = bf16(relu(z16[n]*A+B) + sum relu(z16[src]*A+B))
__global__ __launch_bounds__(256) void k_aggbn(
    const unsigned short* __restrict__ z16,
    const float* __restrict__ stats_in, const float* __restrict__ gv,
    const float* __restrict__ bev,
    const int* __restrict__ offs, const int* __restrict__ bend,
    const int* __restrict__ csr, unsigned short* __restrict__ vout, int N) {
  __shared__ float ABs[128];
  int tid = threadIdx.x;
  if (tid < 64) {
    float inv_n = 1.f / (float)N;
    float mu = stat32(stats_in, tid) * inv_n;
    float var = stat32(stats_in, 64 + tid) * inv_n - mu * mu;
    float A = rsqrtf(var + BN_EPS) * gv[tid];
    ABs[tid] = A;
    ABs[64 + tid] = bev[tid] - mu * A;
  }
  __syncthreads();
  int gid = blockIdx.x * blockDim.x + tid;
  int wid = __builtin_amdgcn_readfirstlane(gid >> 6);
  int lane = tid & 63;
  if (wid >= N) return;
  float A = ABs[lane], B = ABs[64 + lane];
  float acc = fmaxf(bf2f(z16[(size_t)wid * 64 + lane]) * A + B, 0.f);
  int e0 = offs[wid];
  int e1 = ((wid & 511) == 511) ? bend[wid >> 9] : offs[wid + 1];
  int e = e0;
  for (; e + 16 <= e1; e += 16) {
    int s0 = csr[e], s1 = csr[e + 1], s2 = csr[e + 2], s3 = csr[e + 3];
    int s4 = csr[e + 4], s5 = csr[e + 5], s6 = csr[e + 6], s7 = csr[e + 7];
    int s8 = csr[e + 8], s9 = csr[e + 9], sa = csr[e + 10], sb = csr[e + 11];
    int sc = csr[e + 12], sd = csr[e + 13], se = csr[e + 14], sf = csr[e + 15];
    float a0 = bf2f(z16[(size_t)s0 * 64 + lane]);
    float a1 = bf2f(z16[(size_t)s1 * 64 + lane]);
    float a2 = bf2f(z16[(size_t)s2 * 64 + lane]);
    float a3 = bf2f(z16[(size_t)s3 * 64 + lane]);
    float a4 = bf2f(z16[(size_t)s4 * 64 + lane]);
    float a5 = bf2f(z16[(size_t)s5 * 64 + lane]);
    float a6 = bf2f(z16[(size_t)s6 * 64 + lane]);
    float a7 = bf2f(z16[(size_t)s7 * 64 + lane]);
    float a8 = bf2f(z16[(size_t)s8 * 64 + lane]);
    float a9 = bf2f(z16[(size_t)s9 * 64 + lane]);
    float aa = bf2f(z16[(size_t)sa * 64 + lane]);
    float ab = bf2f(z16[(size_t)sb * 64 + lane]);
    float ac = bf2f(z16[(size_t)sc * 64 + lane]);
    float ad = bf2f(z16[(size_t)sd * 64 + lane]);
    float ae = bf2f(z16[(size_t)se * 64 + lane]);
    float af = bf2f(z16[(size_t)sf * 64 + lane]);
    a0 = fmaxf(a0 * A + B, 0.f); a1 = fmaxf(a1 * A + B, 0.f);
    a2 = fmaxf(a2 * A + B, 0.f); a3 = fmaxf(a3 * A + B, 0.f);
    a4 = fmaxf(a4 * A + B, 0.f); a5 = fmaxf(a5 * A + B, 0.f);
    a6 = fmaxf(a6 * A + B, 0.f); a7 = fmaxf(a7 * A + B, 0.f);
    a8 = fmaxf(a8 * A + B, 0.f); a9 = fmaxf(a9 * A + B, 0.f);
    aa = fmaxf(aa * A + B, 0.f); ab = fmaxf(ab * A + B, 0.f);
    ac = fmaxf(ac * A + B, 0.f); ad = fmaxf(ad * A + B, 0.f);
    ae = fmaxf(ae * A + B, 0.f); af = fmaxf(af * A + B, 0.f);
    acc += (((a0 + a1) + (a2 + a3)) + ((a4 + a5) + (a6 + a7))) +
           (((a8 + a9) + (aa + ab)) + ((ac + ad) + (ae + af)));
  }
  for (; e + 4 <= e1; e += 4) {
    int s0 = csr[e], s1 = csr[e + 1], s2 = csr[e + 2], s3 = csr[e + 3];
    float a0 = bf2f(z16[(size_t)s0 * 64 + lane]);
    float a1 = bf2f(z16[(size_t)s1 * 64 + lane]);
    float a2 = bf2f(z16[(size_t)s2 * 64 + lane]);
    float a3 = bf2f(z16[(size_t)s3 * 64 + lane]);
    a0 = fmaxf(a0 * A + B, 0.f); a1 = fmaxf(a1 * A + B, 0.f);
    a2 = fmaxf(a2 * A + B, 0.f); a3 = fmaxf(a3 * A + B, 0.f);
    acc += (a0 + a1) + (a2 + a3);
  }
  for (; e < e1; e++) {
    float a = bf2f(z16[(size_t)csr[e] * 64 + lane]);
    acc += fmaxf(a * A + B, 0.f);
  }
  vout[(size_t)wid * 64 + lane] = f2bf(acc);
}

// MFMA GEMM: 256 rows/block, 4 waves, wave = 64 rows x 64 cols.
// A: bf16 fragments straight from global (BN+ReLU in-register if dobn).
// B: hi/lo bf16 fragments from precomputed global W16 (L1-hot).
// Epilogue: bf16 z store + fp32 column sum/sumsq -> striped stats_out.
__global__ __launch_bounds__(256) void k_gemm2(
    const unsigned short* __restrict__ vin, unsigned short* __restrict__ zout,
    const unsigned short* __restrict__ Wh, const unsigned short* __restrict__ Wl,
    const float* __restrict__ stats_in, const float* __restrict__ gv,
    const float* __restrict__ bev, int dobn,
    float* __restrict__ stats_out, int N) {
  __shared__ float ABs[128];
  __shared__ float red[512];
  int tid = threadIdx.x;
  int n0 = blockIdx.x * 256;
  if (dobn) {
    if (tid < 64) {
      float inv_n = 1.f / (float)N;
      float mu = stat32(stats_in, tid) * inv_n;
      float var = stat32(stats_in, 64 + tid) * inv_n - mu * mu;
      float A = rsqrtf(var + BN_EPS) * gv[tid];
      ABs[tid] = A;
      ABs[64 + tid] = bev[tid] - mu * A;
    }
    __syncthreads();
  }

  int wv = tid >> 6;
  int lane = tid & 63;
  int c = lane & 15;  // col in 16-tile / row in A m-tile
  int q = lane >> 4;  // k-group
  int wrow = n0 + wv * 64;

  // A fragments: a[mt][kb], row = wrow + mt*16 + c, k = kb*32 + 8q + j
  bf16x8 afrag[4][2];
#pragma unroll
  for (int mt = 0; mt < 4; mt++) {
    int row = wrow + mt * 16 + c;
#pragma unroll
    for (int kb = 0; kb < 2; kb++) {
      int col0 = kb * 32 + q * 8;
      bf16x8 a = {0, 0, 0, 0, 0, 0, 0, 0};
      if (row < N) {
        a = *(const bf16x8*)(vin + (size_t)row * 64 + col0);
        if (dobn) {
#pragma unroll
          for (int j = 0; j < 8; j++) {
            float f = bf2f((unsigned short)a[j]) * ABs[col0 + j] +
                      ABs[64 + col0 + j];
            a[j] = (short)f2bf(fmaxf(f, 0.f));
          }
        }
      }
      afrag[mt][kb] = a;
    }
  }

  f32x4 acc[4][4];
#pragma unroll
  for (int mt = 0; mt < 4; mt++)
#pragma unroll
    for (int nt = 0; nt < 4; nt++)
      acc[mt][nt] = (f32x4){0.f, 0.f, 0.f, 0.f};

#pragma unroll
  for (int nt = 0; nt < 4; nt++) {
    int cn = nt * 16 + c;
#pragma unroll
    for (int kb = 0; kb < 2; kb++) {
      int kchunk = kb * 4 + q;
      int kx = ((kchunk ^ (cn & 7)) << 3);
      bf16x8 bhi = *(const bf16x8*)(Wh + cn * 64 + kx);
      bf16x8 blo = *(const bf16x8*)(Wl + cn * 64 + kx);
#pragma unroll
      for (int mt = 0; mt < 4; mt++) {
        acc[mt][nt] = __builtin_amdgcn_mfma_f32_16x16x32_bf16(
            afrag[mt][kb], bhi, acc[mt][nt], 0, 0, 0);
        acc[mt][nt] = __builtin_amdgcn_mfma_f32_16x16x32_bf16(
            afrag[mt][kb], blo, acc[mt][nt], 0, 0, 0);
      }
    }
  }

  // store z (bf16): lane holds rows 4q+r, col nt*16+c
#pragma unroll
  for (int mt = 0; mt < 4; mt++) {
#pragma unroll
    for (int r = 0; r < 4; r++) {
      int row = wrow + mt * 16 + q * 4 + r;
      if (row < N) {
        unsigned short* zr = zout + (size_t)row * 64 + c;
        zr[0] = f2bf(acc[mt][0][r]);
        zr[16] = f2bf(acc[mt][1][r]);
        zr[32] = f2bf(acc[mt][2][r]);
        zr[48] = f2bf(acc[mt][3][r]);
      }
    }
  }

  // column sum / sumsq over this block's rows (phantom rows are exact 0)
  float cs[4], cq[4];
#pragma unroll
  for (int nt = 0; nt < 4; nt++) {
    float s = 0.f, s2 = 0.f;
#pragma unroll
    for (int mt = 0; mt < 4; mt++)
#pragma unroll
      for (int r = 0; r < 4; r++) {
        float v = acc[mt][nt][r];
        s += v;
        s2 += v * v;
      }
    s += __shfl_xor(s, 16);
    s += __shfl_xor(s, 32);
    s2 += __shfl_xor(s2, 16);
    s2 += __shfl_xor(s2, 32);
    cs[nt] = s;
    cq[nt] = s2;
  }
  if (lane < 16) {
#pragma unroll
    for (int nt = 0; nt < 4; nt++) {
      red[wv * 128 + nt * 16 + lane] = cs[nt];
      red[wv * 128 + 64 + nt * 16 + lane] = cq[nt];
    }
  }
  __syncthreads();
  if (tid < 64) {
    float a = red[tid] + red[128 + tid] + red[256 + tid] + red[384 + tid];
    float b = red[64 + tid] + red[192 + tid] + red[320 + tid] + red[448 + tid];
    float* so = stats_out + (blockIdx.x & (NSLOT - 1)) * 128;
    atomicAdd(&so[tid], a);
    atomicAdd(&so[64 + tid], b);
  }
}

// JK heads on MFMA, 4 terms: out[n] = lsm(x@fcW0 + sum_l relu(bn(z_l))@fcW_{l+1}
//                                        + sum_l fcb_l)
// 128 rows/block, 4 waves; B-fragments from precomputed global bh/bl.
__global__ __launch_bounds__(256) void k_head_mfma(
    const unsigned short* __restrict__ x16,
    const unsigned short* __restrict__ z0, const unsigned short* __restrict__ z1,
    const unsigned short* __restrict__ z2, const float* __restrict__ stats,
    const float* __restrict__ gbn, const float* __restrict__ bbn,
    const unsigned short* __restrict__ bh, const unsigned short* __restrict__ bl,
    const float* __restrict__ fcb, float* __restrict__ out, int N) {
  __shared__ float ABs[3 * 128];
  int tid = threadIdx.x;
  if (tid < 64) {
    float inv_n = 1.f / (float)N;
#pragma unroll
    for (int l = 0; l < 3; l++) {
      const float* st = stats + (2 * l + 1) * (NSLOT * 128);
      float mu = stat32(st, tid) * inv_n;
      float var = stat32(st, 64 + tid) * inv_n - mu * mu;
      float A = rsqrtf(var + BN_EPS) * gbn[l * 64 + tid];
      ABs[l * 128 + tid] = A;
      ABs[l * 128 + 64 + tid] = bbn[l * 64 + tid] - mu * A;
    }
  }
  __syncthreads();

  int wv = tid >> 6, lane = tid & 63;
  int c = lane & 15, q = lane >> 4;
  int wrow = blockIdx.x * 128 + wv * 32;

  f32x4 acc[2];
  acc[0] = (f32x4){0.f, 0.f, 0.f, 0.f};
  acc[1] = (f32x4){0.f, 0.f, 0.f, 0.f};
#pragma unroll
  for (int l = 0; l < 4; l++) {
    const unsigned short* z = (l == 0) ? x16 : (l == 1) ? z0 : (l == 2) ? z1
                                                                       : z2;
#pragma unroll
    for (int kb = 0; kb < 2; kb++) {
      int kchunk = kb * 4 + q;
      int kx = ((kchunk ^ (c & 7)) << 3);
      bf16x8 bh_ = *(const bf16x8*)(bh + l * 1024 + c * 64 + kx);
      bf16x8 bl_ = *(const bf16x8*)(bl + l * 1024 + c * 64 + kx);
      int col0 = kb * 32 + q * 8;
#pragma unroll
      for (int mt = 0; mt < 2; mt++) {
        int row = wrow + mt * 16 + c;
        bf16x8 a = {0, 0, 0, 0, 0, 0, 0, 0};
        if (row < N) {
          a = *(const bf16x8*)(z + (size_t)row * 64 + col0);
          if (l > 0) {
            const float* AB = ABs + (l - 1) * 128;
#pragma unroll
            for (int j = 0; j < 8; j++) {
              float f = bf2f((unsigned short)a[j]) * AB[col0 + j] +
                        AB[64 + col0 + j];
              a[j] = (short)f2bf(fmaxf(f, 0.f));
            }
          }
        }
        acc[mt] = __builtin_amdgcn_mfma_f32_16x16x32_bf16(a, bh_, acc[mt],
                                                          0, 0, 0);
        acc[mt] = __builtin_amdgcn_mfma_f32_16x16x32_bf16(a, bl_, acc[mt],
                                                          0, 0, 0);
      }
    }
  }
  // epilogue: + sum_l fcb, log_softmax over cols (c<10), write out
  float cb = 0.f;
  if (c < 10) cb = fcb[c] + fcb[10 + c] + fcb[20 + c] + fcb[30 + c];
#pragma unroll
  for (int mt = 0; mt < 2; mt++) {
    float v[4], vm[4];
#pragma unroll
    for (int r = 0; r < 4; r++) {
      v[r] = acc[mt][r] + cb;
      vm[r] = (c < 10) ? v[r] : -INFINITY;
    }
#pragma unroll
    for (int off = 1; off < 16; off <<= 1) {
#pragma unroll
      for (int r = 0; r < 4; r++) vm[r] = fmaxf(vm[r], __shfl_xor(vm[r], off));
    }
    float sm[4];
#pragma unroll
    for (int r = 0; r < 4; r++) sm[r] = (c < 10) ? expf(v[r] - vm[r]) : 0.f;
#pragma unroll
    for (int off = 1; off < 16; off <<= 1) {
#pragma unroll
      for (int r = 0; r < 4; r++) sm[r] += __shfl_xor(sm[r], off);
    }
#pragma unroll
    for (int r = 0; r < 4; r++) {
      int row = wrow + mt * 16 + q * 4 + r;
      if (row < N && c < 10)
        out[(size_t)row * 10 + c] = v[r] - (logf(sm[r]) + vm[r]);
    }
  }
}

extern "C" void kernel_launch(void* const* d_in, const int* in_sizes, int n_in,
                              void* d_out, int out_size, void* d_ws, size_t ws_size,
                              hipStream_t stream) {
  const float* x = (const float*)d_in[0];
  const int* ei = (const int*)d_in[1];
  const float* W1 = (const float*)d_in[2];
  const float* g1 = (const float*)d_in[4];
  const float* be1 = (const float*)d_in[5];
  const float* W2 = (const float*)d_in[6];
  const float* gbn = (const float*)d_in[8];
  const float* bbn = (const float*)d_in[9];
  const float* fcW = (const float*)d_in[10];
  const float* fcb = (const float*)d_in[11];
  float* out = (float*)d_out;

  const int N = in_sizes[0] / 64;
  const int E = in_sizes[1] / 2;
  const int* src = ei;
  const int* dst = ei + E;

  char* ws = (char*)d_ws;
  size_t off = 0;
  auto alloc = [&](size_t bytes) -> void* {
    void* p = ws + off;
    off = (off + bytes + 255) & ~(size_t)255;
    return p;
  };
  int* bcur = (int*)alloc(NBKT * 4);  // zeroed by memset node
  float* stats = (float*)alloc(6 * NSLOT * 128 * 4);  // zeroed by bucketsort
  int* offs = (int*)alloc((size_t)NBKT * 512 * 4);
  int* bend = (int*)alloc(NBKT * 4);
  int* csr = (int*)alloc((size_t)NBKT * BCAP * 4);
  unsigned short* w16h = (unsigned short*)alloc(6 * 4096 * 2);
  unsigned short* w16l = (unsigned short*)alloc(6 * 4096 * 2);
  unsigned short* bh16 = (unsigned short*)alloc(4 * 1024 * 2);
  unsigned short* bl16 = (unsigned short*)alloc(4 * 1024 * 2);
  unsigned short* x16 = (unsigned short*)alloc((size_t)N * 64 * 2);
  unsigned short* v16 = (unsigned short*)alloc((size_t)N * 64 * 2);
  unsigned short* z1_16 = (unsigned short*)alloc((size_t)N * 64 * 2);
  unsigned short* z16a = (unsigned short*)alloc((size_t)N * 64 * 2);
  unsigned short* z16b = (unsigned short*)alloc((size_t)N * 64 * 2);
  unsigned short* z16c = (unsigned short*)alloc((size_t)N * 64 * 2);
  int2* ep = (int2*)alloc((size_t)NBKT * BCAP * 8);
  (void)ws_size;
  (void)n_in;
  (void)out_size;

  unsigned short* z16l_[3] = {z16a, z16b, z16c};
  int gb = (N + 127) / 128;
  int gb2 = (N + 255) / 256;
  int ab = (N * 64 + 255) / 256;
  int nparts = (E + PCHUNK - 1) / PCHUNK;
  int nconv = (N * 64 / 8 + 255) / 256;
  hipMemsetAsync(bcur, 0, NBKT * 4, stream);
  k_prep<<<112, 256, 0, stream>>>(W1, W2, fcW, w16h, w16l, bh16, bl16);
  k_part_conv<<<nparts + nconv, 256, 0, stream>>>(src, dst, bcur, ep, E,
                                                  nparts, x, x16, N);
  k_bucketsort<<<NBKT, 256, 0, stream>>>(ep, bcur, offs, bend, csr, stats);

  for (int l = 0; l < 3; l++) {
    float* st1 = stats + (2 * l) * (NSLOT * 128);
    float* st2 = stats + (2 * l + 1) * (NSLOT * 128);
    if (l == 0) {
      k_agg<<<ab, 256, 0, stream>>>(x16, offs, bend, csr, v16, N);
    } else {
      float* st2p = stats + (2 * (l - 1) + 1) * (NSLOT * 128);
      k_aggbn<<<ab, 256, 0, stream>>>(z16l_[l - 1], st2p, gbn + (l - 1) * 64,
                                      bbn + (l - 1) * 64, offs, bend, csr,
                                      v16, N);
    }
    k_gemm2<<<gb2, 256, 0, stream>>>(v16, z1_16, w16h + (2 * l) * 4096,
                                     w16l + (2 * l) * 4096, nullptr, nullptr,
                                     nullptr, 0, st1, N);
    k_gemm2<<<gb2, 256, 0, stream>>>(z1_16, z16l_[l], w16h + (2 * l + 1) * 4096,
                                     w16l + (2 * l + 1) * 4096, st1,
                                     g1 + l * 64, be1 + l * 64, 1, st2, N);
  }
  k_head_mfma<<<gb, 256, 0, stream>>>(x16, z16a, z16b, z16c, stats, gbn, bbn,
                                      bh16, bl16, fcb, out, N);
}

// Round 15
// 347.636 us; speedup vs baseline: 1.3791x; 1.0718x over previous
//
#include <hip/hip_runtime.h>
#include <math.h>

// GIN: N=100000 nodes, E=1600000 edges, F=D=64, L=3 layers, C=10 classes.
// R28 == R25 exact restore (best measured: 349.8us, NSLOT=8).
//   R27's 32-slot striping regressed aggbn 46.7->53.7: the 25000-block
//   consumer paid 4096 prologue loads/block (~800MB L2 traffic); producer
//   win was already saturated at 8 slots. Striping width must match the
//   max-grid consumer. R26's fusion regressed (gather needs one-node-
//   per-wave MLP). This config: every component is its A/B-history winner.

#define BN_EPS 1e-5f
#define NBKT 256     // dst buckets (dst>>9)
#define BCAP 12288   // per-bucket edge capacity (mean 8163, +45 sigma)
#define PCHUNK 4096  // edges per partition block
#define NSLOT 8      // stats striping slots (8 = measured optimum)

typedef __attribute__((ext_vector_type(8))) short bf16x8;
typedef __attribute__((ext_vector_type(4))) float f32x4;

__device__ __forceinline__ float bf2f(unsigned short u) {
  return __uint_as_float(((unsigned int)u) << 16);
}
__device__ __forceinline__ unsigned short f2bf(float x) {  // RNE
  unsigned int b = __float_as_uint(x);
  return (unsigned short)((b + 0x7FFFu + ((b >> 16) & 1u)) >> 16);
}

// sum the NSLOT contention slots of a striped stat row
__device__ __forceinline__ float stat8(const float* __restrict__ st, int i) {
  float s = 0.f;
#pragma unroll
  for (int k = 0; k < NSLOT; k++) s += st[k * 128 + i];
  return s;
}

// ---------- weight prep ----------

// once-per-launch: hi/lo bf16 split of all weights into swizzled [n][k].
// mats m=2l -> W1[l], m=2l+1 -> W2[l]; head: fcW[0..3] (cols n>=10 -> 0).
__global__ __launch_bounds__(256) void k_prep(
    const float* __restrict__ W1, const float* __restrict__ W2,
    const float* __restrict__ fcW, unsigned short* __restrict__ wh,
    unsigned short* __restrict__ wl, unsigned short* __restrict__ bh,
    unsigned short* __restrict__ bl) {
  int g = blockIdx.x * 256 + threadIdx.x;
  if (g < 6 * 4096) {
    int m = g >> 12, rem = g & 4095;
    int k = rem >> 6, n = rem & 63;
    const float* W = (m & 1) ? (W2 + (m >> 1) * 4096) : (W1 + (m >> 1) * 4096);
    float w = W[k * 64 + n];
    unsigned short hi = f2bf(w);
    float resid = w - bf2f(hi);
    int kx = (((k >> 3) ^ (n & 7)) << 3) + (k & 7);
    wh[m * 4096 + n * 64 + kx] = hi;
    wl[m * 4096 + n * 64 + kx] = f2bf(resid);
  } else {
    int g2 = g - 6 * 4096;  // [0, 4096)
    if (g2 < 4 * 1024) {
      int l = g2 >> 10, rem = g2 & 1023;
      int n = rem & 15, k = rem >> 4;
      float w = (n < 10) ? fcW[l * 640 + k * 10 + n] : 0.f;
      unsigned short hi = f2bf(w);
      float resid = w - bf2f(hi);
      int idx = l * 1024 + n * 64 + (((k >> 3) ^ (n & 7)) << 3) + (k & 7);
      bh[idx] = hi;
      bl[idx] = f2bf(resid);
    }
  }
}

// ---------- CSR build ----------

// blocks [0,nparts): partition edges into fixed-capacity dst-buckets
// (3KB LDS -> high occupancy); rest: x -> bf16 x16 convert (8 elems/thread).
__global__ __launch_bounds__(256) void k_part_conv(
    const int* __restrict__ src, const int* __restrict__ dst,
    int* __restrict__ bcur, int2* __restrict__ ep, int E, int nparts,
    const float* __restrict__ x, unsigned short* __restrict__ x16, int N) {
  __shared__ int lh[NBKT];
  __shared__ int lbase[NBKT];
  __shared__ int lcur[NBKT];
  int tid = threadIdx.x;
  if ((int)blockIdx.x < nparts) {
    int base = blockIdx.x * PCHUNK;
    int end = min(base + PCHUNK, E);
    lh[tid] = 0;
    lcur[tid] = 0;
    __syncthreads();
    for (int e = base + tid; e < end; e += 256) atomicAdd(&lh[dst[e] >> 9], 1);
    __syncthreads();
    int c = lh[tid];
    lbase[tid] = c ? (tid * BCAP + atomicAdd(&bcur[tid], c)) : 0;
    __syncthreads();
    for (int e = base + tid; e < end; e += 256) {
      int d = dst[e];
      int b = d >> 9;
      int r = atomicAdd(&lcur[b], 1);
      ep[lbase[b] + r] = make_int2(src[e], d);
    }
  } else {
    size_t g = ((size_t)blockIdx.x - nparts) * 256 + tid;
    size_t base = g * 8;
    if (base + 8 <= (size_t)N * 64) {
      float4 t0 = *(const float4*)(x + base);
      float4 t1 = *(const float4*)(x + base + 4);
      *(ushort4*)(x16 + base) =
          make_ushort4(f2bf(t0.x), f2bf(t0.y), f2bf(t0.z), f2bf(t0.w));
      *(ushort4*)(x16 + base + 4) =
          make_ushort4(f2bf(t1.x), f2bf(t1.y), f2bf(t1.z), f2bf(t1.w));
    }
  }
}

// per-bucket LDS counting sort. Emits offs, bend[b], csr. Blk 0 zeroes stats.
__global__ __launch_bounds__(256) void k_bucketsort(
    const int2* __restrict__ ep, const int* __restrict__ bcur,
    int* __restrict__ offs, int* __restrict__ bend, int* __restrict__ csr,
    float* __restrict__ stats) {
  __shared__ int cnt[512];
  __shared__ int ts[256];
  __shared__ int cur[512];
  int t = threadIdx.x;
  int b = blockIdx.x;
  if (b == 0) {
    for (int i = t; i < 6 * NSLOT * 128; i += 256) stats[i] = 0.f;
  }
  int lo = b * BCAP;
  int hi = lo + bcur[b];
  cnt[t] = 0;
  cnt[t + 256] = 0;
  __syncthreads();
  for (int e = lo + t; e < hi; e += 256) atomicAdd(&cnt[ep[e].y & 511], 1);
  __syncthreads();
  int c0 = cnt[2 * t], c1 = cnt[2 * t + 1];
  int s = c0 + c1;
  ts[t] = s;
  __syncthreads();
  for (int o = 1; o < 256; o <<= 1) {
    int add = (t >= o) ? ts[t - o] : 0;
    __syncthreads();
    ts[t] += add;
    __syncthreads();
  }
  int excl = ts[t] - s;
  cur[2 * t] = excl;
  cur[2 * t + 1] = excl + c0;
  int n0 = b << 9;
  offs[n0 + 2 * t] = lo + excl;
  offs[n0 + 2 * t + 1] = lo + excl + c0;
  if (t == 255) bend[b] = lo + ts[255];
  __syncthreads();
  for (int e = lo + t; e < hi; e += 256) {
    int2 p = ep[e];
    int pos = atomicAdd(&cur[p.y & 511], 1);
    csr[lo + pos] = p.x;
  }
}

// ---------- compute ----------

// 16-deep bf16 neighbor gather (no BN): sum of h16[src]
__device__ __forceinline__ float gather_plain(
    const unsigned short* __restrict__ h16, const int* __restrict__ csr,
    int e0, int e1, int lane) {
  float acc = 0.f;
  int e = e0;
  for (; e + 16 <= e1; e += 16) {
    int s0 = csr[e], s1 = csr[e + 1], s2 = csr[e + 2], s3 = csr[e + 3];
    int s4 = csr[e + 4], s5 = csr[e + 5], s6 = csr[e + 6], s7 = csr[e + 7];
    int s8 = csr[e + 8], s9 = csr[e + 9], sa = csr[e + 10], sb = csr[e + 11];
    int sc = csr[e + 12], sd = csr[e + 13], se = csr[e + 14], sf = csr[e + 15];
    float a0 = bf2f(h16[(size_t)s0 * 64 + lane]);
    float a1 = bf2f(h16[(size_t)s1 * 64 + lane]);
    float a2 = bf2f(h16[(size_t)s2 * 64 + lane]);
    float a3 = bf2f(h16[(size_t)s3 * 64 + lane]);
    float a4 = bf2f(h16[(size_t)s4 * 64 + lane]);
    float a5 = bf2f(h16[(size_t)s5 * 64 + lane]);
    float a6 = bf2f(h16[(size_t)s6 * 64 + lane]);
    float a7 = bf2f(h16[(size_t)s7 * 64 + lane]);
    float a8 = bf2f(h16[(size_t)s8 * 64 + lane]);
    float a9 = bf2f(h16[(size_t)s9 * 64 + lane]);
    float aa = bf2f(h16[(size_t)sa * 64 + lane]);
    float ab = bf2f(h16[(size_t)sb * 64 + lane]);
    float ac = bf2f(h16[(size_t)sc * 64 + lane]);
    float ad = bf2f(h16[(size_t)sd * 64 + lane]);
    float ae = bf2f(h16[(size_t)se * 64 + lane]);
    float af = bf2f(h16[(size_t)sf * 64 + lane]);
    acc += (((a0 + a1) + (a2 + a3)) + ((a4 + a5) + (a6 + a7))) +
           (((a8 + a9) + (aa + ab)) + ((ac + ad) + (ae + af)));
  }
  for (; e + 4 <= e1; e += 4) {
    int s0 = csr[e], s1 = csr[e + 1], s2 = csr[e + 2], s3 = csr[e + 3];
    float a0 = bf2f(h16[(size_t)s0 * 64 + lane]);
    float a1 = bf2f(h16[(size_t)s1 * 64 + lane]);
    float a2 = bf2f(h16[(size_t)s2 * 64 + lane]);
    float a3 = bf2f(h16[(size_t)s3 * 64 + lane]);
    acc += (a0 + a1) + (a2 + a3);
  }
  for (; e < e1; e++) acc += bf2f(h16[(size_t)csr[e] * 64 + lane]);
  return acc;
}

// layer-0 aggregation: v16[n] = bf16(x16[n] + sum x16[src])
__global__ __launch_bounds__(256) void k_agg(
    const unsigned short* __restrict__ h16, const int* __restrict__ offs,
    const int* __restrict__ bend, const int* __restrict__ csr,
    unsigned short* __restrict__ vout, int N) {
  int gid = blockIdx.x * blockDim.x + threadIdx.x;
  int wid = __builtin_amdgcn_readfirstlane(gid >> 6);
  int lane = threadIdx.x & 63;
  if (wid >= N) return;
  int e0 = offs[wid];
  int e1 = ((wid & 511) == 511) ? bend[wid >> 9] : offs[wid + 1];
  float acc = bf2f(h16[(size_t)wid * 64 + lane]) +
              gather_plain(h16, csr, e0, e1, lane);
  vout[(size_t)wid * 64 + lane] = f2bf(acc);
}

// BN+ReLU aggregation: v16[n] = bf16(relu(z16[n]*A+B) + sum relu(z16[src]*A+B))
__global__ __launch_bounds__(256) void k_aggbn(
    const unsigned short* __restrict__ z16,
    const float* __restrict__ stats_in, const float* __restrict__ gv,
    const float* __restrict__ bev,
    const int* __restrict__ offs, const int* __restrict__ bend,
    const int* __restrict__ csr, unsigned short* __restrict__ vout, int N) {
  __shared__ float ABs[128];
  int tid = threadIdx.x;
  if (tid < 64) {
    float inv_n = 1.f / (float)N;
    float mu = stat8(stats_in, tid) * inv_n;
    float var = stat8(stats_in, 64 + tid) * inv_n - mu * mu;
    float A = rsqrtf(var + BN_EPS) * gv[tid];
    ABs[tid] = A;
    ABs[64 + tid] = bev[tid] - mu * A;
  }
  __syncthreads();
  int gid = blockIdx.x * blockDim.x + tid;
  int wid = __builtin_amdgcn_readfirstlane(gid >> 6);
  int lane = tid & 63;
  if (wid >= N) return;
  float A = ABs[lane], B = ABs[64 + lane];
  float acc = fmaxf(bf2f(z16[(size_t)wid * 64 + lane]) * A + B, 0.f);
  int e0 = offs[wid];
  int e1 = ((wid & 511) == 511) ? bend[wid >> 9] : offs[wid + 1];
  int e = e0;
  for (; e + 16 <= e1; e += 16) {
    int s0 = csr[e], s1 = csr[e + 1], s2 = csr[e + 2], s3 = csr[e + 3];
    int s4 = csr[e + 4], s5 = csr[e + 5], s6 = csr[e + 6], s7 = csr[e + 7];
    int s8 = csr[e + 8], s9 = csr[e + 9], sa = csr[e + 10], sb = csr[e + 11];
    int sc = csr[e + 12], sd = csr[e + 13], se = csr[e + 14], sf = csr[e + 15];
    float a0 = bf2f(z16[(size_t)s0 * 64 + lane]);
    float a1 = bf2f(z16[(size_t)s1 * 64 + lane]);
    float a2 = bf2f(z16[(size_t)s2 * 64 + lane]);
    float a3 = bf2f(z16[(size_t)s3 * 64 + lane]);
    float a4 = bf2f(z16[(size_t)s4 * 64 + lane]);
    float a5 = bf2f(z16[(size_t)s5 * 64 + lane]);
    float a6 = bf2f(z16[(size_t)s6 * 64 + lane]);
    float a7 = bf2f(z16[(size_t)s7 * 64 + lane]);
    float a8 = bf2f(z16[(size_t)s8 * 64 + lane]);
    float a9 = bf2f(z16[(size_t)s9 * 64 + lane]);
    float aa = bf2f(z16[(size_t)sa * 64 + lane]);
    float ab = bf2f(z16[(size_t)sb * 64 + lane]);
    float ac = bf2f(z16[(size_t)sc * 64 + lane]);
    float ad = bf2f(z16[(size_t)sd * 64 + lane]);
    float ae = bf2f(z16[(size_t)se * 64 + lane]);
    float af = bf2f(z16[(size_t)sf * 64 + lane]);
    a0 = fmaxf(a0 * A + B, 0.f); a1 = fmaxf(a1 * A + B, 0.f);
    a2 = fmaxf(a2 * A + B, 0.f); a3 = fmaxf(a3 * A + B, 0.f);
    a4 = fmaxf(a4 * A + B, 0.f); a5 = fmaxf(a5 * A + B, 0.f);
    a6 = fmaxf(a6 * A + B, 0.f); a7 = fmaxf(a7 * A + B, 0.f);
    a8 = fmaxf(a8 * A + B, 0.f); a9 = fmaxf(a9 * A + B, 0.f);
    aa = fmaxf(aa * A + B, 0.f); ab = fmaxf(ab * A + B, 0.f);
    ac = fmaxf(ac * A + B, 0.f); ad = fmaxf(ad * A + B, 0.f);
    ae = fmaxf(ae * A + B, 0.f); af = fmaxf(af * A + B, 0.f);
    acc += (((a0 + a1) + (a2 + a3)) + ((a4 + a5) + (a6 + a7))) +
           (((a8 + a9) + (aa + ab)) + ((ac + ad) + (ae + af)));
  }
  for (; e + 4 <= e1; e += 4) {
    int s0 = csr[e], s1 = csr[e + 1], s2 = csr[e + 2], s3 = csr[e + 3];
    float a0 = bf2f(z16[(size_t)s0 * 64 + lane]);
    float a1 = bf2f(z16[(size_t)s1 * 64 + lane]);
    float a2 = bf2f(z16[(size_t)s2 * 64 + lane]);
    float a3 = bf2f(z16[(size_t)s3 * 64 + lane]);
    a0 = fmaxf(a0 * A + B, 0.f); a1 = fmaxf(a1 * A + B, 0.f);
    a2 = fmaxf(a2 * A + B, 0.f); a3 = fmaxf(a3 * A + B, 0.f);
    acc += (a0 + a1) + (a2 + a3);
  }
  for (; e < e1; e++) {
    float a = bf2f(z16[(size_t)csr[e] * 64 + lane]);
    acc += fmaxf(a * A + B, 0.f);
  }
  vout[(size_t)wid * 64 + lane] = f2bf(acc);
}

// MFMA GEMM: 256 rows/block, 4 waves, wave = 64 rows x 64 cols.
// A: bf16 fragments straight from global (BN+ReLU in-register if dobn).
// B: hi/lo bf16 fragments from precomputed global W16 (L1-hot).
// Epilogue: bf16 z store + fp32 column sum/sumsq -> striped stats_out.
__global__ __launch_bounds__(256) void k_gemm2(
    const unsigned short* __restrict__ vin, unsigned short* __restrict__ zout,
    const unsigned short* __restrict__ Wh, const unsigned short* __restrict__ Wl,
    const float* __restrict__ stats_in, const float* __restrict__ gv,
    const float* __restrict__ bev, int dobn,
    float* __restrict__ stats_out, int N) {
  __shared__ float ABs[128];
  __shared__ float red[512];
  int tid = threadIdx.x;
  int n0 = blockIdx.x * 256;
  if (dobn) {
    if (tid < 64) {
      float inv_n = 1.f / (float)N;
      float mu = stat8(stats_in, tid) * inv_n;
      float var = stat8(stats_in, 64 + tid) * inv_n - mu * mu;
      float A = rsqrtf(var + BN_EPS) * gv[tid];
      ABs[tid] = A;
      ABs[64 + tid] = bev[tid] - mu * A;
    }
    __syncthreads();
  }

  int wv = tid >> 6;
  int lane = tid & 63;
  int c = lane & 15;  // col in 16-tile / row in A m-tile
  int q = lane >> 4;  // k-group
  int wrow = n0 + wv * 64;

  // A fragments: a[mt][kb], row = wrow + mt*16 + c, k = kb*32 + 8q + j
  bf16x8 afrag[4][2];
#pragma unroll
  for (int mt = 0; mt < 4; mt++) {
    int row = wrow + mt * 16 + c;
#pragma unroll
    for (int kb = 0; kb < 2; kb++) {
      int col0 = kb * 32 + q * 8;
      bf16x8 a = {0, 0, 0, 0, 0, 0, 0, 0};
      if (row < N) {
        a = *(const bf16x8*)(vin + (size_t)row * 64 + col0);
        if (dobn) {
#pragma unroll
          for (int j = 0; j < 8; j++) {
            float f = bf2f((unsigned short)a[j]) * ABs[col0 + j] +
                      ABs[64 + col0 + j];
            a[j] = (short)f2bf(fmaxf(f, 0.f));
          }
        }
      }
      afrag[mt][kb] = a;
    }
  }

  f32x4 acc[4][4];
#pragma unroll
  for (int mt = 0; mt < 4; mt++)
#pragma unroll
    for (int nt = 0; nt < 4; nt++)
      acc[mt][nt] = (f32x4){0.f, 0.f, 0.f, 0.f};

#pragma unroll
  for (int nt = 0; nt < 4; nt++) {
    int cn = nt * 16 + c;
#pragma unroll
    for (int kb = 0; kb < 2; kb++) {
      int kchunk = kb * 4 + q;
      int kx = ((kchunk ^ (cn & 7)) << 3);
      bf16x8 bhi = *(const bf16x8*)(Wh + cn * 64 + kx);
      bf16x8 blo = *(const bf16x8*)(Wl + cn * 64 + kx);
#pragma unroll
      for (int mt = 0; mt < 4; mt++) {
        acc[mt][nt] = __builtin_amdgcn_mfma_f32_16x16x32_bf16(
            afrag[mt][kb], bhi, acc[mt][nt], 0, 0, 0);
        acc[mt][nt] = __builtin_amdgcn_mfma_f32_16x16x32_bf16(
            afrag[mt][kb], blo, acc[mt][nt], 0, 0, 0);
      }
    }
  }

  // store z (bf16): lane holds rows 4q+r, col nt*16+c
#pragma unroll
  for (int mt = 0; mt < 4; mt++) {
#pragma unroll
    for (int r = 0; r < 4; r++) {
      int row = wrow + mt * 16 + q * 4 + r;
      if (row < N) {
        unsigned short* zr = zout + (size_t)row * 64 + c;
        zr[0] = f2bf(acc[mt][0][r]);
        zr[16] = f2bf(acc[mt][1][r]);
        zr[32] = f2bf(acc[mt][2][r]);
        zr[48] = f2bf(acc[mt][3][r]);
      }
    }
  }

  // column sum / sumsq over this block's rows (phantom rows are exact 0)
  float cs[4], cq[4];
#pragma unroll
  for (int nt = 0; nt < 4; nt++) {
    float s = 0.f, s2 = 0.f;
#pragma unroll
    for (int mt = 0; mt < 4; mt++)
#pragma unroll
      for (int r = 0; r < 4; r++) {
        float v = acc[mt][nt][r];
        s += v;
        s2 += v * v;
      }
    s += __shfl_xor(s, 16);
    s += __shfl_xor(s, 32);
    s2 += __shfl_xor(s2, 16);
    s2 += __shfl_xor(s2, 32);
    cs[nt] = s;
    cq[nt] = s2;
  }
  if (lane < 16) {
#pragma unroll
    for (int nt = 0; nt < 4; nt++) {
      red[wv * 128 + nt * 16 + lane] = cs[nt];
      red[wv * 128 + 64 + nt * 16 + lane] = cq[nt];
    }
  }
  __syncthreads();
  if (tid < 64) {
    float a = red[tid] + red[128 + tid] + red[256 + tid] + red[384 + tid];
    float b = red[64 + tid] + red[192 + tid] + red[320 + tid] + red[448 + tid];
    float* so = stats_out + (blockIdx.x & (NSLOT - 1)) * 128;
    atomicAdd(&so[tid], a);
    atomicAdd(&so[64 + tid], b);
  }
}

// JK heads on MFMA, 4 terms: out[n] = lsm(x@fcW0 + sum_l relu(bn(z_l))@fcW_{l+1}
//                                        + sum_l fcb_l)
// 128 rows/block, 4 waves; B-fragments from precomputed global bh/bl.
__global__ __launch_bounds__(256) void k_head_mfma(
    const unsigned short* __restrict__ x16,
    const unsigned short* __restrict__ z0, const unsigned short* __restrict__ z1,
    const unsigned short* __restrict__ z2, const float* __restrict__ stats,
    const float* __restrict__ gbn, const float* __restrict__ bbn,
    const unsigned short* __restrict__ bh, const unsigned short* __restrict__ bl,
    const float* __restrict__ fcb, float* __restrict__ out, int N) {
  __shared__ float ABs[3 * 128];
  int tid = threadIdx.x;
  if (tid < 64) {
    float inv_n = 1.f / (float)N;
#pragma unroll
    for (int l = 0; l < 3; l++) {
      const float* st = stats + (2 * l + 1) * (NSLOT * 128);
      float mu = stat8(st, tid) * inv_n;
      float var = stat8(st, 64 + tid) * inv_n - mu * mu;
      float A = rsqrtf(var + BN_EPS) * gbn[l * 64 + tid];
      ABs[l * 128 + tid] = A;
      ABs[l * 128 + 64 + tid] = bbn[l * 64 + tid] - mu * A;
    }
  }
  __syncthreads();

  int wv = tid >> 6, lane = tid & 63;
  int c = lane & 15, q = lane >> 4;
  int wrow = blockIdx.x * 128 + wv * 32;

  f32x4 acc[2];
  acc[0] = (f32x4){0.f, 0.f, 0.f, 0.f};
  acc[1] = (f32x4){0.f, 0.f, 0.f, 0.f};
#pragma unroll
  for (int l = 0; l < 4; l++) {
    const unsigned short* z = (l == 0) ? x16 : (l == 1) ? z0 : (l == 2) ? z1
                                                                       : z2;
#pragma unroll
    for (int kb = 0; kb < 2; kb++) {
      int kchunk = kb * 4 + q;
      int kx = ((kchunk ^ (c & 7)) << 3);
      bf16x8 bh_ = *(const bf16x8*)(bh + l * 1024 + c * 64 + kx);
      bf16x8 bl_ = *(const bf16x8*)(bl + l * 1024 + c * 64 + kx);
      int col0 = kb * 32 + q * 8;
#pragma unroll
      for (int mt = 0; mt < 2; mt++) {
        int row = wrow + mt * 16 + c;
        bf16x8 a = {0, 0, 0, 0, 0, 0, 0, 0};
        if (row < N) {
          a = *(const bf16x8*)(z + (size_t)row * 64 + col0);
          if (l > 0) {
            const float* AB = ABs + (l - 1) * 128;
#pragma unroll
            for (int j = 0; j < 8; j++) {
              float f = bf2f((unsigned short)a[j]) * AB[col0 + j] +
                        AB[64 + col0 + j];
              a[j] = (short)f2bf(fmaxf(f, 0.f));
            }
          }
        }
        acc[mt] = __builtin_amdgcn_mfma_f32_16x16x32_bf16(a, bh_, acc[mt],
                                                          0, 0, 0);
        acc[mt] = __builtin_amdgcn_mfma_f32_16x16x32_bf16(a, bl_, acc[mt],
                                                          0, 0, 0);
      }
    }
  }
  // epilogue: + sum_l fcb, log_softmax over cols (c<10), write out
  float cb = 0.f;
  if (c < 10) cb = fcb[c] + fcb[10 + c] + fcb[20 + c] + fcb[30 + c];
#pragma unroll
  for (int mt = 0; mt < 2; mt++) {
    float v[4], vm[4];
#pragma unroll
    for (int r = 0; r < 4; r++) {
      v[r] = acc[mt][r] + cb;
      vm[r] = (c < 10) ? v[r] : -INFINITY;
    }
#pragma unroll
    for (int off = 1; off < 16; off <<= 1) {
#pragma unroll
      for (int r = 0; r < 4; r++) vm[r] = fmaxf(vm[r], __shfl_xor(vm[r], off));
    }
    float sm[4];
#pragma unroll
    for (int r = 0; r < 4; r++) sm[r] = (c < 10) ? expf(v[r] - vm[r]) : 0.f;
#pragma unroll
    for (int off = 1; off < 16; off <<= 1) {
#pragma unroll
      for (int r = 0; r < 4; r++) sm[r] += __shfl_xor(sm[r], off);
    }
#pragma unroll
    for (int r = 0; r < 4; r++) {
      int row = wrow + mt * 16 + q * 4 + r;
      if (row < N && c < 10)
        out[(size_t)row * 10 + c] = v[r] - (logf(sm[r]) + vm[r]);
    }
  }
}

extern "C" void kernel_launch(void* const* d_in, const int* in_sizes, int n_in,
                              void* d_out, int out_size, void* d_ws, size_t ws_size,
                              hipStream_t stream) {
  const float* x = (const float*)d_in[0];
  const int* ei = (const int*)d_in[1];
  const float* W1 = (const float*)d_in[2];
  const float* g1 = (const float*)d_in[4];
  const float* be1 = (const float*)d_in[5];
  const float* W2 = (const float*)d_in[6];
  const float* gbn = (const float*)d_in[8];
  const float* bbn = (const float*)d_in[9];
  const float* fcW = (const float*)d_in[10];
  const float* fcb = (const float*)d_in[11];
  float* out = (float*)d_out;

  const int N = in_sizes[0] / 64;
  const int E = in_sizes[1] / 2;
  const int* src = ei;
  const int* dst = ei + E;

  char* ws = (char*)d_ws;
  size_t off = 0;
  auto alloc = [&](size_t bytes) -> void* {
    void* p = ws + off;
    off = (off + bytes + 255) & ~(size_t)255;
    return p;
  };
  int* bcur = (int*)alloc(NBKT * 4);  // zeroed by memset node
  float* stats = (float*)alloc(6 * NSLOT * 128 * 4);  // zeroed by bucketsort
  int* offs = (int*)alloc((size_t)NBKT * 512 * 4);
  int* bend = (int*)alloc(NBKT * 4);
  int* csr = (int*)alloc((size_t)NBKT * BCAP * 4);
  unsigned short* w16h = (unsigned short*)alloc(6 * 4096 * 2);
  unsigned short* w16l = (unsigned short*)alloc(6 * 4096 * 2);
  unsigned short* bh16 = (unsigned short*)alloc(4 * 1024 * 2);
  unsigned short* bl16 = (unsigned short*)alloc(4 * 1024 * 2);
  unsigned short* x16 = (unsigned short*)alloc((size_t)N * 64 * 2);
  unsigned short* v16 = (unsigned short*)alloc((size_t)N * 64 * 2);
  unsigned short* z1_16 = (unsigned short*)alloc((size_t)N * 64 * 2);
  unsigned short* z16a = (unsigned short*)alloc((size_t)N * 64 * 2);
  unsigned short* z16b = (unsigned short*)alloc((size_t)N * 64 * 2);
  unsigned short* z16c = (unsigned short*)alloc((size_t)N * 64 * 2);
  int2* ep = (int2*)alloc((size_t)NBKT * BCAP * 8);
  (void)ws_size;
  (void)n_in;
  (void)out_size;

  unsigned short* z16l_[3] = {z16a, z16b, z16c};
  int gb = (N + 127) / 128;
  int gb2 = (N + 255) / 256;
  int ab = (N * 64 + 255) / 256;
  int nparts = (E + PCHUNK - 1) / PCHUNK;
  int nconv = (N * 64 / 8 + 255) / 256;
  hipMemsetAsync(bcur, 0, NBKT * 4, stream);
  k_prep<<<112, 256, 0, stream>>>(W1, W2, fcW, w16h, w16l, bh16, bl16);
  k_part_conv<<<nparts + nconv, 256, 0, stream>>>(src, dst, bcur, ep, E,
                                                  nparts, x, x16, N);
  k_bucketsort<<<NBKT, 256, 0, stream>>>(ep, bcur, offs, bend, csr, stats);

  for (int l = 0; l < 3; l++) {
    float* st1 = stats + (2 * l) * (NSLOT * 128);
    float* st2 = stats + (2 * l + 1) * (NSLOT * 128);
    if (l == 0) {
      k_agg<<<ab, 256, 0, stream>>>(x16, offs, bend, csr, v16, N);
    } else {
      float* st2p = stats + (2 * (l - 1) + 1) * (NSLOT * 128);
      k_aggbn<<<ab, 256, 0, stream>>>(z16l_[l - 1], st2p, gbn + (l - 1) * 64,
                                      bbn + (l - 1) * 64, offs, bend, csr,
                                      v16, N);
    }
    k_gemm2<<<gb2, 256, 0, stream>>>(v16, z1_16, w16h + (2 * l) * 4096,
                                     w16l + (2 * l) * 4096, nullptr, nullptr,
                                     nullptr, 0, st1, N);
    k_gemm2<<<gb2, 256, 0, stream>>>(z1_16, z16l_[l], w16h + (2 * l + 1) * 4096,
                                     w16l + (2 * l + 1) * 4096, st1,
                                     g1 + l * 64, be1 + l * 64, 1, st2, N);
  }
  k_head_mfma<<<gb, 256, 0, stream>>>(x16, z16a, z16b, z16c, stats, gbn, bbn,
                                      bh16, bl16, fcb, out, N);
}